// Round 1
// baseline (1176.283 us; speedup 1.0000x reference)
//
#include <hip/hip_runtime.h>
#include <hip/hip_bf16.h>

typedef unsigned int u32;
typedef unsigned short u16;
typedef __attribute__((ext_vector_type(8))) short bf16x8;
typedef __attribute__((ext_vector_type(8))) unsigned short u16x8;
typedef __attribute__((ext_vector_type(4))) float f32x4;
typedef __attribute__((ext_vector_type(4))) float f4;

#define SLEN 512
#define BATCH 256
#define HS_TOTAL 33554432   // S*B*H
#define MAXSEG 131072
#define MAXTILES 2048

// ws layout (bytes):
//     0: u32 nseg counter
//  4096: u32 hist[513]
//  8192: u32 offs[513]
// 16384: f32 bias[1024]
//  1MB : u16 wpack[2][64][8][64][8]   (1MB)
//  2MB : u32 segs[131072]             (512KB)
//  2.5MB: u32 sorted[131072]          (512KB)

__device__ __forceinline__ u16 f2bf(float f) {
  u32 u = __builtin_bit_cast(u32, f);
  u += 0x7fffu + ((u >> 16) & 1u);
  return (u16)(u >> 16);
}
__device__ __forceinline__ float sigm(float x) {
  return __builtin_amdgcn_rcpf(1.f + __builtin_amdgcn_exp2f(-1.44269504088896f * x));
}
__device__ __forceinline__ float tanh_(float x) {
  return 1.f - 2.f * __builtin_amdgcn_rcpf(1.f + __builtin_amdgcn_exp2f(2.88539008177793f * x));
}

// ---------- prep: bias sum ----------
__global__ void k_bias(const float* __restrict__ bih, const float* __restrict__ bhh,
                       float* __restrict__ bias) {
  int g = blockIdx.x * 256 + threadIdx.x;
  bias[g] = bih[g] + bhh[g];
}

// ---------- prep: pack W_ih^T, W_hh^T into MFMA B-fragment order (bf16) ----------
// wpack[blk = which*512 + nt*8 + kt][lane][j] = W[nt*16+(lane&15)][kt*32+(lane>>4)*8+j]
__global__ void k_pack(const float* __restrict__ Wih, const float* __restrict__ Whh,
                       u16* __restrict__ wpack) {
  int blk = blockIdx.x;
  int ln = threadIdx.x;
  const float* W = (blk >> 9) ? Whh : Wih;
  int nt = (blk >> 3) & 63, kt = blk & 7;
  int g = nt * 16 + (ln & 15);
  int kb = kt * 32 + (ln >> 4) * 8;
  const float* src = W + g * 256 + kb;
  u16x8 v;
#pragma unroll
  for (int j = 0; j < 8; j++) v[j] = f2bf(src[j]);
  *(u16x8*)(wpack + (size_t)blk * 512 + ln * 8) = v;
}

// ---------- prep: segment extraction ----------
// seg record: b(8) | start(9)<<8 | len(10)<<17 | h0flag<<27
__global__ void k_segscan(const float* __restrict__ done, u32* __restrict__ cnt,
                          u32* __restrict__ hist, u32* __restrict__ segs) {
  __shared__ u32 lhist[513];
  int t = threadIdx.x;
  for (int i = t; i < 513; i += 256) lhist[i] = 0;
  __syncthreads();
  int wv = t >> 6, ln = t & 63;
  int b = blockIdx.x * 4 + wv;
  u32 myrec[8];
  int mycnt = 0;
  for (int j = 0; j < 8; j++) {
    int s = ln * 8 + j;
    float d = done[s * 256 + b];
    bool bnd = (s == 0) || (d != 0.f);
    if (bnd) {
      int s2 = s + 1;
      while (s2 < 512 && done[s2 * 256 + b] == 0.f) s2++;
      u32 len = (u32)(s2 - s);
      u32 h0f = (s == 0 && d == 0.f) ? 1u : 0u;
      myrec[mycnt++] = (u32)b | ((u32)s << 8) | (len << 17) | (h0f << 27);
    }
  }
  // wave-aggregate the append
  u32 incl = (u32)mycnt;
  for (int d = 1; d < 64; d <<= 1) {
    u32 o = (u32)__shfl_up((int)incl, d);
    if (ln >= d) incl += o;
  }
  u32 total = (u32)__shfl((int)incl, 63);
  u32 base = 0;
  if (ln == 0) base = atomicAdd(cnt, total);
  base = (u32)__shfl((int)base, 0);
  u32 off = base + incl - (u32)mycnt;
  for (int i = 0; i < mycnt; i++) {
    segs[off + i] = myrec[i];
    atomicAdd(&lhist[(myrec[i] >> 17) & 1023], 1u);
  }
  __syncthreads();
  for (int i = t; i < 513; i += 256)
    if (lhist[i]) atomicAdd(&hist[i], lhist[i]);
}

// ---------- prep: offsets for descending-length sort ----------
__global__ void k_prefix(const u32* __restrict__ hist, u32* __restrict__ offs) {
  __shared__ u32 h[513];
  int t = threadIdx.x;
  if (t < 513) h[t] = hist[t];
  __syncthreads();
  if (t < 513) {
    u32 s = 0;
    for (int l = t + 1; l < 513; l++) s += h[l];
    offs[t] = s;
  }
}

// ---------- prep: scatter into sorted order ----------
__global__ void k_scatter(const u32* __restrict__ cnt, const u32* __restrict__ segs,
                          u32* __restrict__ offs, u32* __restrict__ sorted) {
  __shared__ u32 lh[513];
  __shared__ u32 gb[513];
  int t = threadIdx.x;
  for (int i = t; i < 513; i += 512) lh[i] = 0;
  __syncthreads();
  u32 n = *cnt;
  u32 i = blockIdx.x * 512 + t;
  u32 rec = 0, lpos = 0;
  bool v = (i < n);
  if (v) {
    rec = segs[i];
    lpos = atomicAdd(&lh[(rec >> 17) & 1023], 1u);
  }
  __syncthreads();
  for (int j = t; j < 513; j += 512) gb[j] = lh[j] ? atomicAdd(&offs[j], lh[j]) : 0u;
  __syncthreads();
  if (v) sorted[gb[(rec >> 17) & 1023] + lpos] = rec;
}

// ---------- main: 64-segment tiles, lockstep chain steps, fused MFMA ----------
__global__ __launch_bounds__(512, 2) void k_main(
    const float* __restrict__ inp, const float* __restrict__ h0,
    const float* __restrict__ c0, const u16* __restrict__ wpack,
    const float* __restrict__ bias, const u32* __restrict__ cnt,
    const u32* __restrict__ sorted, float* __restrict__ out) {
  __shared__ __align__(16) u16 Ax[64 * 256];
  __shared__ __align__(16) u16 Ah[64 * 256];
  __shared__ u32 meta[64];
  __shared__ int s_h0;

  u32 nseg = *cnt;
  u32 base = blockIdx.x * 64u;
  if (base >= nseg) return;
  int tid = threadIdx.x;
  if (tid < 64) {
    u32 i = base + (u32)tid;
    meta[tid] = (i < nseg) ? sorted[i] : 0u;
  }
  if (tid == 0) s_h0 = 0;
  __syncthreads();
  if (tid < 64 && ((meta[tid] >> 27) & 1u)) s_h0 = 1;
  __syncthreads();
  const int maxlen = (int)((meta[0] >> 17) & 1023u);
  const int has0 = s_h0;
  const int w = tid >> 6, lane = tid & 63;
  const int srow = tid >> 3, scg = tid & 7;
  const u32 srec = meta[srow];
  const int s_len = (int)((srec >> 17) & 1023u);
  const int s_b = (int)(srec & 255u);
  const int s_st = (int)((srec >> 8) & 511u);
  char* AxB = (char*)&Ax[0];
  char* AhB = (char*)&Ah[0];
  const int swzS = (srow & 7) << 4;

  // init Ah: zeros, or h0 row for h0-carry segments
  {
    bool hh = ((srec >> 27) & 1u);
    const float* hp = h0 + (srec & 255u) * 256 + scg * 32;
#pragma unroll
    for (int u = 0; u < 4; u++) {
      u16x8 v;
      if (hh) {
        const f4* p = (const f4*)(hp + u * 8);
        f4 x0 = p[0], x1 = p[1];
        v = (u16x8){f2bf(x0[0]), f2bf(x0[1]), f2bf(x0[2]), f2bf(x0[3]),
                    f2bf(x1[0]), f2bf(x1[1]), f2bf(x1[2]), f2bf(x1[3])};
      } else {
        v = (u16x8){0, 0, 0, 0, 0, 0, 0, 0};
      }
      *(u16x8*)(AhB + srow * 512 + ((scg * 64 + u * 16) ^ swzS)) = v;
    }
  }

  // c state + bias registers
  float c_reg[4][2][4];
  float bias_r[4][2];
#pragma unroll
  for (int q = 0; q < 4; q++)
#pragma unroll
    for (int t2 = 0; t2 < 2; t2++)
      bias_r[q][t2] = bias[q * 256 + w * 32 + t2 * 16 + (lane & 15)];
#pragma unroll
  for (int mt = 0; mt < 4; mt++)
#pragma unroll
    for (int reg = 0; reg < 4; reg++) {
      int m = mt * 16 + ((lane >> 4) << 2) + reg;
      u32 rr = meta[m];
      bool hh = (rr >> 27) & 1u;
#pragma unroll
      for (int t2 = 0; t2 < 2; t2++) {
        int j = w * 32 + t2 * 16 + (lane & 15);
        c_reg[mt][t2][reg] = hh ? c0[(rr & 255u) * 256 + j] : 0.f;
      }
    }

  const u16* wp0 = wpack;
  const u16* wp1 = wpack + (size_t)512 * 512;  // which=1 block offset in u16s

  for (int r = 0; r < maxlen; r++) {
    // ---- stage X row -> bf16 LDS (swizzled) ----
    if (r < s_len) {
      const f4* p = (const f4*)(inp + ((size_t)((s_st + r) * 256 + s_b)) * 256 + scg * 32);
#pragma unroll
      for (int u = 0; u < 4; u++) {
        f4 x0 = p[2 * u], x1 = p[2 * u + 1];
        u16x8 v = (u16x8){f2bf(x0[0]), f2bf(x0[1]), f2bf(x0[2]), f2bf(x0[3]),
                          f2bf(x1[0]), f2bf(x1[1]), f2bf(x1[2]), f2bf(x1[3])};
        *(u16x8*)(AxB + srow * 512 + ((scg * 64 + u * 16) ^ swzS)) = v;
      }
    } else if (r == 0) {
      u16x8 z = (u16x8){0, 0, 0, 0, 0, 0, 0, 0};
#pragma unroll
      for (int u = 0; u < 4; u++)
        *(u16x8*)(AxB + srow * 512 + ((scg * 64 + u * 16) ^ swzS)) = z;
    }
    __syncthreads();

    // ---- MFMA: gates = bias + X*Wih^T (+ H*Whh^T) ----
    f32x4 acc[4][4][2];
#pragma unroll
    for (int mt = 0; mt < 4; mt++)
#pragma unroll
      for (int q = 0; q < 4; q++)
#pragma unroll
        for (int t2 = 0; t2 < 2; t2++) {
          float bv = bias_r[q][t2];
          acc[mt][q][t2] = (f32x4){bv, bv, bv, bv};
        }

#pragma unroll
    for (int kt = 0; kt < 8; kt++) {
      bf16x8 a[4];
#pragma unroll
      for (int mt = 0; mt < 4; mt++) {
        int row = mt * 16 + (lane & 15);
        a[mt] = *(const bf16x8*)(AxB + row * 512 +
                                 ((kt * 64 + ((lane >> 4) << 4)) ^ ((row & 7) << 4)));
      }
#pragma unroll
      for (int q = 0; q < 4; q++)
#pragma unroll
        for (int t2 = 0; t2 < 2; t2++) {
          int nt = q * 16 + w * 2 + t2;
          bf16x8 bf = *(const bf16x8*)(wp0 + ((size_t)(nt * 8 + kt) * 64 + lane) * 8);
#pragma unroll
          for (int mt = 0; mt < 4; mt++)
            acc[mt][q][t2] =
                __builtin_amdgcn_mfma_f32_16x16x32_bf16(a[mt], bf, acc[mt][q][t2], 0, 0, 0);
        }
    }
    if (r > 0 || has0) {
#pragma unroll
      for (int kt = 0; kt < 8; kt++) {
        bf16x8 a[4];
#pragma unroll
        for (int mt = 0; mt < 4; mt++) {
          int row = mt * 16 + (lane & 15);
          a[mt] = *(const bf16x8*)(AhB + row * 512 +
                                   ((kt * 64 + ((lane >> 4) << 4)) ^ ((row & 7) << 4)));
        }
#pragma unroll
        for (int q = 0; q < 4; q++)
#pragma unroll
          for (int t2 = 0; t2 < 2; t2++) {
            int nt = q * 16 + w * 2 + t2;
            bf16x8 bf = *(const bf16x8*)(wp1 + ((size_t)(nt * 8 + kt) * 64 + lane) * 8);
#pragma unroll
            for (int mt = 0; mt < 4; mt++)
              acc[mt][q][t2] =
                  __builtin_amdgcn_mfma_f32_16x16x32_bf16(a[mt], bf, acc[mt][q][t2], 0, 0, 0);
          }
      }
    }
    __syncthreads();  // all waves done reading Ah/Ax before h writes

    // ---- activations + state update + writes ----
#pragma unroll
    for (int mt = 0; mt < 4; mt++)
#pragma unroll
      for (int reg = 0; reg < 4; reg++) {
        int m = mt * 16 + ((lane >> 4) << 2) + reg;
        u32 rr = meta[m];
        int len = (int)((rr >> 17) & 1023u);
        if (r < len) {
          int bb = (int)(rr & 255u);
          int st = (int)((rr >> 8) & 511u);
          int s = st + r;
#pragma unroll
          for (int t2 = 0; t2 < 2; t2++) {
            float iv = acc[mt][0][t2][reg];
            float fv = acc[mt][1][t2][reg];
            float gv = acc[mt][2][t2][reg];
            float ov = acc[mt][3][t2][reg];
            float cn = sigm(fv) * c_reg[mt][t2][reg] + sigm(iv) * tanh_(gv);
            float hn = sigm(ov) * tanh_(cn);
            c_reg[mt][t2][reg] = cn;
            int j = w * 32 + t2 * 16 + (lane & 15);
            out[((size_t)(s * 256 + bb)) * 256 + j] = hn;
            *((u16*)(AhB + m * 512 + ((2 * j) ^ ((m & 7) << 4)))) = f2bf(hn);
            if (s == 511) {
              out[HS_TOTAL + bb * 256 + j] = hn;
              out[HS_TOTAL + 65536 + bb * 256 + j] = cn;
            }
          }
        }
      }
    __syncthreads();  // Ah complete for next step; Ax safe to overwrite
  }
}

extern "C" void kernel_launch(void* const* d_in, const int* in_sizes, int n_in,
                              void* d_out, int out_size, void* d_ws, size_t ws_size,
                              hipStream_t stream) {
  const float* inp = (const float*)d_in[0];
  const float* h0 = (const float*)d_in[1];
  const float* c0 = (const float*)d_in[2];
  const float* done = (const float*)d_in[3];
  const float* Wih = (const float*)d_in[4];
  const float* Whh = (const float*)d_in[5];
  const float* bih = (const float*)d_in[6];
  const float* bhh = (const float*)d_in[7];
  float* out = (float*)d_out;

  char* W = (char*)d_ws;
  u32* cnt = (u32*)W;
  u32* hist = (u32*)(W + 4096);
  u32* offs = (u32*)(W + 8192);
  float* bias = (float*)(W + 16384);
  u16* wpack = (u16*)(W + (1 << 20));
  u32* segs = (u32*)(W + (2 << 20));
  u32* sorted = (u32*)(W + (2 << 20) + (1 << 19));

  hipMemsetAsync(d_ws, 0, 8192, stream);
  k_bias<<<4, 256, 0, stream>>>(bih, bhh, bias);
  k_pack<<<1024, 64, 0, stream>>>(Wih, Whh, wpack);
  k_segscan<<<64, 256, 0, stream>>>(done, cnt, hist, segs);
  k_prefix<<<1, 1024, 0, stream>>>(hist, offs);
  k_scatter<<<256, 512, 0, stream>>>(cnt, segs, offs, sorted);
  k_main<<<MAXTILES, 512, 0, stream>>>(inp, h0, c0, wpack, bias, cnt, sorted, out);
}